// Round 4
// baseline (252.145 us; speedup 1.0000x reference)
//
#include <hip/hip_runtime.h>
#include <cstdint>

// GraphormerMultiHeadAttention on MI355X (gfx950), bf16 MFMA path.
// B=16, N=512, D=1024, H=16, hd=64. scale = D^-0.5 = 1/32.
//
// R3 -> R4 changes:
//  - attn computes S^T = K·Q^T so the MFMA C-layout of S^T directly matches
//    the B-operand layout of mfma_f32_16x16x16 (k=quad*4+i): P stays in
//    registers (no sP LDS round-trip, no 16x ds_write_b16/iter). PV runs as
//    O^T = V^T·P^T via mfma_f32_16x16x16f16; V is stored f16 (more precise
//    than bf16 for N(0,1) data). lsum is one scalar/lane, reduced twice.
//  - prep (x cast, 4 weight casts, bias permute) fused into one kernel.
//  - bias permuted to the (jb,r) order of the S^T fragments.

typedef unsigned short u16;
typedef unsigned int   u32;
typedef __attribute__((ext_vector_type(8))) short bf8;     // 8 x bf16 (4 VGPRs)
typedef __attribute__((ext_vector_type(4))) _Float16 h4;   // 4 x f16  (2 VGPRs)
typedef __attribute__((ext_vector_type(4))) float f4;      // 4 x f32 accum

__device__ __forceinline__ u16 f2bf(float x) {
  u32 u = __float_as_uint(x);
  u += 0x7FFF + ((u >> 16) & 1);        // round-to-nearest-even
  return (u16)(u >> 16);
}

__device__ __forceinline__ float bf2f(u16 x) {
  return __uint_as_float(((u32)x) << 16);
}

__device__ __forceinline__ u16 f2h(float x) {
  union { _Float16 h; u16 u; } c;
  c.h = (_Float16)x;                    // v_cvt_f16_f32 (RNE)
  return c.u;
}

// async global->LDS, 16B per lane. LDS dest = wave-uniform base + lane*16.
__device__ __forceinline__ void gl2lds16(const void* g, void* l) {
  __builtin_amdgcn_global_load_lds(
      (const __attribute__((address_space(1))) u32*)g,
      (__attribute__((address_space(3))) u32*)l, 16, 0, 0);
}

// ---------------- fused prep kernel ----------------
// blocks [0,4096)    : cast x (8M floats) -> bf16
// blocks [4096,6144) : cast Wq,Wk,Wv,Wo -> bf16
// blocks [6144,7168) : bias = bf16(sp+ed) permuted for attn fragments:
//   per (b,qt,jt) block, lane tid=(wave,quad,l16) gets 16 values (32B chunk),
//   element idx = jb*4 + r  ->  row q = qt*64+wave*16+l16,
//                               col j = jt*64+jb*16+quad*4+r

__global__ __launch_bounds__(256) void prep_kernel(
    const float* __restrict__ x, const float* __restrict__ sp,
    const float* __restrict__ ed,
    const float* __restrict__ W0, const float* __restrict__ W1,
    const float* __restrict__ W2, const float* __restrict__ W3,
    uint4* __restrict__ xb,
    uint4* __restrict__ d0, uint4* __restrict__ d1,
    uint4* __restrict__ d2, uint4* __restrict__ d3,
    u16* __restrict__ Bp) {
  const int bid = blockIdx.x;
  const int tid = threadIdx.x;
  if (bid < 6144) {
    const float* src;
    uint4* dst;
    int j;
    if (bid < 4096) {
      src = x; dst = xb; j = bid * 256 + tid;
    } else {
      const int i = (bid - 4096) * 256 + tid;      // 0 .. 524287
      const int w = i >> 17;
      j = i & 131071;
      src = (w == 0) ? W0 : (w == 1) ? W1 : (w == 2) ? W2 : W3;
      dst = (w == 0) ? d0 : (w == 1) ? d1 : (w == 2) ? d2 : d3;
    }
    const float4* s = (const float4*)src;
    const float4 a = s[2 * j], c = s[2 * j + 1];
    uint4 o;
    o.x = (u32)f2bf(a.x) | ((u32)f2bf(a.y) << 16);
    o.y = (u32)f2bf(a.z) | ((u32)f2bf(a.w) << 16);
    o.z = (u32)f2bf(c.x) | ((u32)f2bf(c.y) << 16);
    o.w = (u32)f2bf(c.z) | ((u32)f2bf(c.w) << 16);
    dst[j] = o;
  } else {
    const int id = bid - 6144;                     // 0 .. 1023
    const int jt = id & 7, qt = (id >> 3) & 7, b = id >> 6;
    const int wave = tid >> 6, quad = (tid >> 4) & 3, l16 = tid & 15;
    const int row = (qt << 6) + (wave << 4) + l16;
    union { u16 a[16]; uint4 v[2]; } tmp;
#pragma unroll
    for (int jb = 0; jb < 4; jb++) {
#pragma unroll
      for (int r = 0; r < 4; r++) {
        const int col = (jt << 6) + (jb << 4) + (quad << 2) + r;
        const size_t idx = ((size_t)b << 18) + (size_t)row * 512 + col;
        tmp.a[jb * 4 + r] = f2bf(sp[idx] + ed[idx]);
      }
    }
    uint4* out = (uint4*)Bp + ((((size_t)b * 8 + qt) * 8 + jt) * 256 + tid) * 2;
    out[0] = tmp.v[0];
    out[1] = tmp.v[1];
  }
}

// ---------------- GEMM core: C(128x128) = A(128x1024) * Bt(128x1024)^T ----------------
// A row-major [M][1024], Bt row-major [Nout][1024] (computes A @ Bt^T).
// LDS tiles are [128 rows][8 chunks of 16B], slot (r,c) holds global chunk c^(r&7).

__device__ __forceinline__ void gemm_core(const u16* __restrict__ A,
                                          const u16* __restrict__ Bt,
                                          int m0, int n0,
                                          u16* lA, u16* lB, f4 acc[4][4]) {
  const int tid  = threadIdx.x;
  const int wave = tid >> 6;
  const int lane = tid & 63;
  const int quad = lane >> 4;
  const int l16  = lane & 15;
  const int wm   = (wave >> 1) << 6;
  const int wn   = (wave & 1) << 6;
  const int srow = tid >> 3;
  const int scol = ((tid & 7) ^ (srow & 7)) << 3;   // swizzled source chunk
  const int c0   = (quad ^ (l16 & 7)) << 3;         // swizzled read offset, kk=0

  f4 zero = {0.f, 0.f, 0.f, 0.f};
#pragma unroll
  for (int mi = 0; mi < 4; mi++)
#pragma unroll
    for (int ni = 0; ni < 4; ni++) acc[mi][ni] = zero;

  const u16* Ab = A  + (size_t)(m0 + srow) * 1024 + scol;
  const u16* Bb = Bt + (size_t)(n0 + srow) * 1024 + scol;

  for (int k0 = 0; k0 < 1024; k0 += 64) {
    __syncthreads();   // protect LDS from previous iteration's readers
#pragma unroll
    for (int i = 0; i < 4; i++) {
      gl2lds16(Ab + (size_t)(i << 5) * 1024 + k0,
               (char*)lA + (((i << 8) + (wave << 6)) << 4));
      gl2lds16(Bb + (size_t)(i << 5) * 1024 + k0,
               (char*)lB + (((i << 8) + (wave << 6)) << 4));
    }
    __syncthreads();   // drains vmcnt(0) -> tiles visible
#pragma unroll
    for (int kk = 0; kk < 64; kk += 32) {
      const int o = c0 ^ kk;
      bf8 af[4], bfr[4];
#pragma unroll
      for (int mi = 0; mi < 4; mi++)
        af[mi] = *(const bf8*)(lA + (wm + (mi << 4) + l16) * 64 + o);
#pragma unroll
      for (int ni = 0; ni < 4; ni++)
        bfr[ni] = *(const bf8*)(lB + (wn + (ni << 4) + l16) * 64 + o);
#pragma unroll
      for (int mi = 0; mi < 4; mi++)
#pragma unroll
        for (int ni = 0; ni < 4; ni++)
          acc[mi][ni] = __builtin_amdgcn_mfma_f32_16x16x32_bf16(
              af[mi], bfr[ni], acc[mi][ni], 0, 0, 0);
    }
  }
}

// ---------------- QKV projection ----------------
// XCD remap: flat bits [2:0]=m_lo [5:3]=n_tile [8:6]=m_hi [10:9]=proj.

__global__ __launch_bounds__(256) void qkv_kernel(
    const u16* __restrict__ xb, const u16* __restrict__ wq,
    const u16* __restrict__ wk, const u16* __restrict__ wv,
    u16* __restrict__ Qh, u16* __restrict__ Kh, u16* __restrict__ Vt) {
  __shared__ __align__(16) u16 lA[128 * 64];
  __shared__ __align__(16) u16 lB[128 * 64];
  const int flat = blockIdx.x + (blockIdx.y << 3) + (blockIdx.z << 9);
  const int m_tile = (flat & 7) | (((flat >> 6) & 7) << 3);
  const int n_tile = (flat >> 3) & 7;
  const int proj = flat >> 9;
  const int m0 = m_tile << 7, n0 = n_tile << 7;
  const u16* W = (proj == 0) ? wq : (proj == 1) ? wk : wv;
  f4 acc[4][4];
  gemm_core(xb, W, m0, n0, lA, lB, acc);

  const int tid = threadIdx.x, wave = tid >> 6, lane = tid & 63;
  const int quad = lane >> 4, l16 = lane & 15;
  const int wm = (wave >> 1) << 6, wn = (wave & 1) << 6;

  if (proj == 2) {
    // V: [B,H,hd,512] in f16; r=0..3 are consecutive n -> pack ushort4 (8B)
#pragma unroll
    for (int mi = 0; mi < 4; mi++) {
      const int gmb = m0 + wm + (mi << 4) + (quad << 2);
      const int b = gmb >> 9, nb = gmb & 511;
#pragma unroll
      for (int ni = 0; ni < 4; ni++) {
        const int gn = n0 + wn + (ni << 4) + l16;
        const int h = gn >> 6, hdi = gn & 63;
        ushort4 pk;
        pk.x = f2h(acc[mi][ni][0]);
        pk.y = f2h(acc[mi][ni][1]);
        pk.z = f2h(acc[mi][ni][2]);
        pk.w = f2h(acc[mi][ni][3]);
        *(ushort4*)(Vt + ((size_t)((b << 4) + h) * 64 + hdi) * 512 + nb) = pk;
      }
    }
  } else {
    u16* dst = (proj == 0) ? Qh : Kh;
#pragma unroll
    for (int mi = 0; mi < 4; mi++) {
#pragma unroll
      for (int r = 0; r < 4; r++) {
        const int gm = m0 + wm + (mi << 4) + (quad << 2) + r;
        const int b = gm >> 9, n = gm & 511;
#pragma unroll
        for (int ni = 0; ni < 4; ni++) {
          const int gn = n0 + wn + (ni << 4) + l16;
          const int h = gn >> 6, hdi = gn & 63;
          dst[((size_t)((b << 4) + h) * 512 + n) * 64 + hdi] = f2bf(acc[mi][ni][r]);
        }
      }
    }
  }
}

// ---------------- output projection ----------------
// XCD remap: flat bits [2:0]=m_lo [5:3]=n_tile [8:6]=m_hi.

__global__ __launch_bounds__(256) void oproj_kernel(const u16* __restrict__ Ob,
                                                    const u16* __restrict__ wo,
                                                    float* __restrict__ out) {
  __shared__ __align__(16) u16 lA[128 * 64];
  __shared__ __align__(16) u16 lB[128 * 64];
  const int flat = blockIdx.x + (blockIdx.y << 3);
  const int m0 = ((flat & 7) | (((flat >> 6) & 7) << 3)) << 7;
  const int n0 = ((flat >> 3) & 7) << 7;
  f4 acc[4][4];
  gemm_core(Ob, wo, m0, n0, lA, lB, acc);

  const int tid = threadIdx.x, wave = tid >> 6, lane = tid & 63;
  const int quad = lane >> 4, l16 = lane & 15;
  const int wm = (wave >> 1) << 6, wn = (wave & 1) << 6;
#pragma unroll
  for (int mi = 0; mi < 4; mi++)
#pragma unroll
    for (int r = 0; r < 4; r++) {
      const int gm = m0 + wm + (mi << 4) + (quad << 2) + r;
#pragma unroll
      for (int ni = 0; ni < 4; ni++) {
        const int gn = n0 + wn + (ni << 4) + l16;
        out[(size_t)gm * 1024 + gn] = acc[mi][ni][r];
      }
    }
}

// ---------------- fused attention: one wg per (64 q-rows, h, b) ----------------
// Q,K: [B,H,512,64] bf16.  Vt: [B,H,64,512] f16.  Bp: permuted bias chunks.
// Ob out: [B*512,1024] bf16 (= [B,N,H,hd]).
// XCD remap: flat bits [2:0]=b_lo [5:3]=q_tile [9:6]=h [10]=b_hi.
// S^T = K.Q^T via mfma 16x16x32_bf16 (C-layout: col=q=l16, row=j=quad*4+r);
// that C-layout IS the B-operand layout of mfma 16x16x16 (k=quad*4+i), so
// P goes straight to PV: O^T = V^T.P^T via mfma_f32_16x16x16f16. No sP.
// Softmax without max-subtraction (logits bounded); one scalar sum per lane.

__global__ __launch_bounds__(256) void attn_kernel(
    const u16* __restrict__ Qh, const u16* __restrict__ Kh,
    const u16* __restrict__ Vt, const u16* __restrict__ Bp,
    u16* __restrict__ Ob) {
  __shared__ __align__(16) u16 sQ[64 * 64];
  __shared__ __align__(16) u16 sK[64 * 64];
  __shared__ __align__(16) u16 sV[64 * 64];        // [hd][j] layout, f16 bits
  const int flat = blockIdx.x + (blockIdx.y << 3) + (blockIdx.z << 7);
  const int qt = (flat >> 3) & 7;
  const int h  = (flat >> 6) & 15;
  const int b  = (flat & 7) | (((flat >> 10) & 1) << 3);
  const int q0 = qt << 6;
  const int tid = threadIdx.x, wave = tid >> 6, lane = tid & 63;
  const int quad = lane >> 4, l16 = lane & 15;
  const int c0  = (quad ^ (l16 & 7)) << 3;                 // swizzled read offset
  const int swb = (((tid & 7) ^ ((tid >> 3) & 7)) << 4);   // swizzled staging byte off

  const u16* Qg = Qh + ((size_t)((b << 4) + h) * 512 + q0) * 64;
  const u16* Kg = Kh + (size_t)((b << 4) + h) * 512 * 64;
  const u16* Vg = Vt + (size_t)((b << 4) + h) * 64 * 512;
  const uint4* Bpg = (const uint4*)Bp + (((size_t)b * 8 + qt) * 8 * 256 + tid) * 2;

  // stage Q tile (swizzled), then read this wave's Q fragments once
#pragma unroll
  for (int i = 0; i < 2; i++) {
    const int e = (i << 8) + tid;
    gl2lds16((const char*)Qg + (e >> 3) * 128 + swb,
             (char*)sQ + (((i << 8) + (wave << 6)) << 4));
  }
  __syncthreads();
  const bf8 bq0 = *(const bf8*)(sQ + ((wave << 4) + l16) * 64 + c0);
  const bf8 bq1 = *(const bf8*)(sQ + ((wave << 4) + l16) * 64 + (c0 ^ 32));

  f4 o[4];
  f4 zero = {0.f, 0.f, 0.f, 0.f};
#pragma unroll
  for (int i = 0; i < 4; i++) o[i] = zero;
  float lsum = 0.f;

  for (int j0 = 0; j0 < 512; j0 += 64) {
    // bias chunk for this j-tile: 32B/lane, issued before barriers
    const uint4 bc0 = Bpg[(j0 >> 6) * 512];
    const uint4 bc1 = Bpg[(j0 >> 6) * 512 + 1];
    const u32 bw[8] = {bc0.x, bc0.y, bc0.z, bc0.w, bc1.x, bc1.y, bc1.z, bc1.w};

    __syncthreads();
#pragma unroll
    for (int i = 0; i < 2; i++) {
      const int e = (i << 8) + tid;
      gl2lds16((const char*)Kg + (size_t)j0 * 128 + (e >> 3) * 128 + swb,
               (char*)sK + (((i << 8) + (wave << 6)) << 4));
      gl2lds16((const char*)Vg + (size_t)(e >> 3) * 1024 + j0 * 2 + swb,
               (char*)sV + (((i << 8) + (wave << 6)) << 4));
    }
    __syncthreads();

    // S^T tiles + exp, P fragments stay in registers
    h4 pf[4];
#pragma unroll
    for (int jb = 0; jb < 4; jb++) {
      bf8 a0 = *(const bf8*)(sK + ((jb << 4) + l16) * 64 + c0);
      bf8 a1 = *(const bf8*)(sK + ((jb << 4) + l16) * 64 + (c0 ^ 32));
      f4 s = zero;
      s = __builtin_amdgcn_mfma_f32_16x16x32_bf16(a0, bq0, s, 0, 0, 0);
      s = __builtin_amdgcn_mfma_f32_16x16x32_bf16(a1, bq1, s, 0, 0, 0);
#pragma unroll
      for (int r = 0; r < 4; r++) {
        const u32 w = bw[jb * 2 + (r >> 1)];
        const float bias = bf2f((r & 1) ? (u16)(w >> 16) : (u16)(w & 0xFFFF));
        const float ev = __expf(s[r] * 0.03125f + bias);
        lsum += ev;
        pf[jb][r] = (_Float16)ev;
      }
    }

    // O^T += V^T . P^T  (A = V-frag from sV, B = P-frag in registers)
#pragma unroll
    for (int db = 0; db < 4; db++) {
#pragma unroll
      for (int jb = 0; jb < 4; jb++) {
        const h4 va = *(const h4*)(sV + ((db << 4) + l16) * 64 +
                                   ((((jb << 1) + (quad >> 1)) ^ (l16 & 7)) << 3) +
                                   ((quad & 1) << 2));
        o[db] = __builtin_amdgcn_mfma_f32_16x16x16f16(va, pf[jb], o[db], 0, 0, 0);
      }
    }
  }

  // row sum: lane's 16 values all belong to q-row l16 of this wave;
  // combine the 4 quads, then normalize and store (d = db*16+quad*4+r).
  lsum += __shfl_xor(lsum, 16);
  lsum += __shfl_xor(lsum, 32);
  const float inv = 1.f / lsum;
  const int q = q0 + (wave << 4) + l16;
#pragma unroll
  for (int db = 0; db < 4; db++) {
    ushort4 pk;
    pk.x = f2bf(o[db][0] * inv);
    pk.y = f2bf(o[db][1] * inv);
    pk.z = f2bf(o[db][2] * inv);
    pk.w = f2bf(o[db][3] * inv);
    *(ushort4*)(Ob + (size_t)((b << 9) + q) * 1024 + (h << 6) + (db << 4) +
                (quad << 2)) = pk;
  }
}

// ---------------- launch ----------------

extern "C" void kernel_launch(void* const* d_in, const int* in_sizes, int n_in,
                              void* d_out, int out_size, void* d_ws, size_t ws_size,
                              hipStream_t stream) {
  const float* x  = (const float*)d_in[0];
  const float* sp = (const float*)d_in[1];
  const float* ed = (const float*)d_in[2];
  const float* Wq = (const float*)d_in[3];
  const float* Wk = (const float*)d_in[4];
  const float* Wv = (const float*)d_in[5];
  const float* Wo = (const float*)d_in[6];
  float* out = (float*)d_out;

  char* w = (char*)d_ws;
  u16* xb  = (u16*)(w);                  // 16 MB  : x bf16 [8192][1024]
  u16* wqb = (u16*)(w + 16777216);       // 2 MB
  u16* wkb = (u16*)(w + 18874368);
  u16* wvb = (u16*)(w + 20971520);
  u16* wob = (u16*)(w + 23068672);
  u16* Qh  = (u16*)(w + 25165824);       // 16 MB  : [B,H,512,64] bf16
  u16* Kh  = (u16*)(w + 41943040);       // 16 MB
  u16* Vt  = (u16*)(w + 58720256);       // 16 MB  : [B,H,64,512] f16
  u16* Ob  = (u16*)(w + 75497472);       // 16 MB  : [8192][1024] bf16
  u16* Bp  = (u16*)(w + 92274688);       // 8 MB   : permuted bf16(sp+ed)

  prep_kernel<<<7168, 256, 0, stream>>>(x, sp, ed, Wq, Wk, Wv, Wo,
                                        (uint4*)xb, (uint4*)wqb, (uint4*)wkb,
                                        (uint4*)wvb, (uint4*)wob, Bp);
  qkv_kernel<<<dim3(8, 64, 3), 256, 0, stream>>>(xb, wqb, wkb, wvb, Qh, Kh, Vt);
  attn_kernel<<<dim3(8, 16, 16), 256, 0, stream>>>(Qh, Kh, Vt, Bp, Ob);
  oproj_kernel<<<dim3(8, 64, 1), 256, 0, stream>>>(Ob, wob, out);
}